// Round 1
// baseline (289.417 us; speedup 1.0000x reference)
//
#include <hip/hip_runtime.h>

using bf16x8 = __attribute__((ext_vector_type(8))) short;
using f32x4  = __attribute__((ext_vector_type(4))) float;

static constexpr int NN = 2048;   // nodes
static constexpr int NB = 32;     // batch
static constexpr int NC = 32;     // channels (C1 == C2)

__device__ __forceinline__ unsigned short f2bf(float f) {
    unsigned int u = __float_as_uint(f);
    u += 0x7FFFu + ((u >> 16) & 1u);   // round-to-nearest-even
    return (unsigned short)(u >> 16);
}

// ---------------------------------------------------------------------------
// Projection: XWt[b][c][m] = bf16( sum_f X[b][m][f] * W[f][c] )   (no bias/relu)
// grid = (NN/256, NB), block = 256. One thread per node-row m.
// ---------------------------------------------------------------------------
template<int INCH>
__global__ void proj_kernel(const float* __restrict__ X, const float* __restrict__ W,
                            unsigned short* __restrict__ XWt)
{
    __shared__ float wlds[INCH * NC];
    const int b = blockIdx.y;
    const int m = blockIdx.x * 256 + threadIdx.x;
    for (int i = threadIdx.x; i < INCH * NC; i += 256) wlds[i] = W[i];
    __syncthreads();

    const float* xrow = X + ((size_t)b * NN + m) * INCH;
    float acc[NC];
#pragma unroll
    for (int c = 0; c < NC; ++c) acc[c] = 0.f;

    for (int f = 0; f < INCH; f += 4) {
        const float4 v = *reinterpret_cast<const float4*>(xrow + f);
        const float xv[4] = {v.x, v.y, v.z, v.w};
#pragma unroll
        for (int j = 0; j < 4; ++j) {
#pragma unroll
            for (int c = 0; c < NC; ++c)
                acc[c] += xv[j] * wlds[(f + j) * NC + c];
        }
    }

    unsigned short* outp = XWt + (size_t)b * NC * NN + m;
#pragma unroll
    for (int c = 0; c < NC; ++c) outp[(size_t)c * NN] = f2bf(acc[c]);
}

// ---------------------------------------------------------------------------
// GCN layer GEMM:  H = relu(A @ XW + bias),  A [NN x NN] fp32, XW^T bf16 [NC][NN].
// grid = (NN/64, NB), block = 256 (4 waves, each wave owns a 16-row x 32-col tile).
// WRITE_H=true : write H fp32 [b][n][NC]   (layer 1)
// WRITE_H=false: skip H, accumulate column sums into pooled[b][c]  (layer 2 + pool)
// ---------------------------------------------------------------------------
template<bool WRITE_H>
__global__ void gcn_gemm(const float* __restrict__ A, const unsigned short* __restrict__ Bt,
                         const float* __restrict__ bias, float* __restrict__ Hout,
                         float* __restrict__ pooled)
{
    const int b    = blockIdx.y;
    const int wave = threadIdx.x >> 6;
    const int lane = threadIdx.x & 63;
    const int lr   = lane & 15;   // A-row / B-col / C-col index within tile
    const int kg   = lane >> 4;   // k-group (0..3), 8 k-elements each

    const int r0 = blockIdx.x * 64 + wave * 16;

    const float*          ap  = A  + ((size_t)b * NN + (r0 + lr)) * NN + kg * 8;
    const unsigned short* bp0 = Bt + ((size_t)b * NC + lr) * NN + kg * 8;
    const unsigned short* bp1 = bp0 + (size_t)16 * NN;

    f32x4 acc0 = {0.f, 0.f, 0.f, 0.f};
    f32x4 acc1 = {0.f, 0.f, 0.f, 0.f};

#pragma unroll 2
    for (int k = 0; k < NN; k += 32) {
        const float4 x0 = *reinterpret_cast<const float4*>(ap);
        const float4 x1 = *reinterpret_cast<const float4*>(ap + 4);
        const bf16x8 bv0 = *reinterpret_cast<const bf16x8*>(bp0);
        const bf16x8 bv1 = *reinterpret_cast<const bf16x8*>(bp1);
        ap += 32; bp0 += 32; bp1 += 32;

        bf16x8 af;
        af[0] = (short)f2bf(x0.x); af[1] = (short)f2bf(x0.y);
        af[2] = (short)f2bf(x0.z); af[3] = (short)f2bf(x0.w);
        af[4] = (short)f2bf(x1.x); af[5] = (short)f2bf(x1.y);
        af[6] = (short)f2bf(x1.z); af[7] = (short)f2bf(x1.w);

        acc0 = __builtin_amdgcn_mfma_f32_16x16x32_bf16(af, bv0, acc0, 0, 0, 0);
        acc1 = __builtin_amdgcn_mfma_f32_16x16x32_bf16(af, bv1, acc1, 0, 0, 0);
    }

    const float bias0 = bias[lr];
    const float bias1 = bias[lr + 16];

    if constexpr (WRITE_H) {
#pragma unroll
        for (int j = 0; j < 4; ++j) {
            const int row = r0 + kg * 4 + j;
            float* hp = Hout + ((size_t)b * NN + row) * NC;
            hp[lr]      = fmaxf(acc0[j] + bias0, 0.f);
            hp[lr + 16] = fmaxf(acc1[j] + bias1, 0.f);
        }
    } else {
        float s0 = 0.f, s1 = 0.f;
#pragma unroll
        for (int j = 0; j < 4; ++j) {
            s0 += fmaxf(acc0[j] + bias0, 0.f);
            s1 += fmaxf(acc1[j] + bias1, 0.f);
        }
        // reduce over the 4 row-groups (lane bits 4,5): all lanes with same lr share col
        s0 += __shfl_xor(s0, 16); s0 += __shfl_xor(s0, 32);
        s1 += __shfl_xor(s1, 16); s1 += __shfl_xor(s1, 32);
        if (kg == 0) {
            atomicAdd(&pooled[b * NC + lr],      s0);
            atomicAdd(&pooled[b * NC + 16 + lr], s1);
        }
    }
}

// ---------------------------------------------------------------------------
// FC head: out[b] = sum_h relu(pooled[b,:] @ Wf1[:,h] + bf1[h]) * Wf2[h] + bf2
// grid = NB blocks, 512 threads (one per hidden unit).
// ---------------------------------------------------------------------------
__global__ void head_kernel(const float* __restrict__ pooled,
                            const float* __restrict__ Wf1, const float* __restrict__ bf1,
                            const float* __restrict__ Wf2, const float* __restrict__ bf2,
                            float* __restrict__ out)
{
    const int b = blockIdx.x;
    const int h = threadIdx.x;   // 0..511

    float dot = 0.f;
#pragma unroll
    for (int c = 0; c < NC; ++c)
        dot += pooled[b * NC + c] * Wf1[c * 512 + h];

    const float v   = fmaxf(dot + bf1[h], 0.f);
    float part      = v * Wf2[h];

#pragma unroll
    for (int off = 32; off >= 1; off >>= 1)
        part += __shfl_xor(part, off);

    __shared__ float red[8];
    if ((threadIdx.x & 63) == 0) red[threadIdx.x >> 6] = part;
    __syncthreads();
    if (threadIdx.x == 0) {
        float s = 0.f;
#pragma unroll
        for (int i = 0; i < 8; ++i) s += red[i];
        out[b] = s + bf2[0];
    }
}

// ---------------------------------------------------------------------------
extern "C" void kernel_launch(void* const* d_in, const int* in_sizes, int n_in,
                              void* d_out, int out_size, void* d_ws, size_t ws_size,
                              hipStream_t stream)
{
    const float* x   = (const float*)d_in[0];
    const float* a   = (const float*)d_in[1];
    const float* W1  = (const float*)d_in[2];
    const float* b1  = (const float*)d_in[3];
    const float* W2  = (const float*)d_in[4];
    const float* b2  = (const float*)d_in[5];
    const float* Wf1 = (const float*)d_in[6];
    const float* bf1 = (const float*)d_in[7];
    const float* Wf2 = (const float*)d_in[8];
    const float* bf2 = (const float*)d_in[9];
    float* out = (float*)d_out;

    char* ws = (char*)d_ws;
    unsigned short* xwt1 = (unsigned short*)(ws);                    // 4 MB  [b][c][m] bf16
    float*          h1   = (float*)(ws + (4ull << 20));              // 8 MB  [b][m][c] fp32
    unsigned short* xwt2 = (unsigned short*)(ws + (12ull << 20));    // 4 MB  [b][c][m] bf16
    float*          pooled = (float*)(ws + (16ull << 20));           // 4 KB  [b][c] fp32

    hipMemsetAsync(pooled, 0, NB * NC * sizeof(float), stream);

    dim3 pgrid(NN / 256, NB);
    proj_kernel<64><<<pgrid, 256, 0, stream>>>(x, W1, xwt1);

    dim3 ggrid(NN / 64, NB);
    gcn_gemm<true><<<ggrid, 256, 0, stream>>>(a, xwt1, b1, h1, nullptr);

    proj_kernel<32><<<pgrid, 256, 0, stream>>>(h1, W2, xwt2);

    gcn_gemm<false><<<ggrid, 256, 0, stream>>>(a, xwt2, b2, nullptr, pooled);

    head_kernel<<<dim3(NB), 512, 0, stream>>>(pooled, Wf1, bf1, Wf2, bf2, out);
}